// Round 10
// baseline (11361.480 us; speedup 1.0000x reference)
//
#include <hip/hip_runtime.h>
#include <math.h>

// Problem constants
#define B 2048
#define T 128
#define H 512
#define NC 3
#define NO 5
#define G3H 1536
#define BHE ((size_t)B * H)

typedef _Float16 half8 __attribute__((ext_vector_type(8)));
typedef float float4v __attribute__((ext_vector_type(4)));
typedef unsigned int uint32;
typedef unsigned int uint4v __attribute__((ext_vector_type(4)));

#define LO_SCALE 1024.0f
#define INV_LO (1.0f / 1024.0f)
#define F16_MIN_NORM 6.103515625e-05f

__device__ __forceinline__ float sigmoidf_(float x) { return 1.0f / (1.0f + __expf(-x)); }

__device__ __forceinline__ void split_f16(float a, _Float16* hi, _Float16* lo) {
    _Float16 h = (_Float16)a;
    if (fabsf(a) < F16_MIN_NORM) h = (_Float16)0.0f;
    *hi = h;
    *lo = (_Float16)((a - (float)h) * LO_SCALE);
}

// element (row,k) of a 512-col matrix stored at row*512 + swzk(row,k)
__device__ __forceinline__ int swzk(int row, int k) {
    return (k & ~63) | ((((k >> 3) & 7) ^ (row & 7)) << 3) | (k & 7);
}

// weights: normal cached async 16B global->LDS (stays in XCD L2)
__device__ __forceinline__ void stage16w(const _Float16* gp, _Float16* lp) {
    __builtin_amdgcn_global_load_lds(
        (const __attribute__((address_space(1))) unsigned int*)gp,
        (__attribute__((address_space(3))) unsigned int*)lp, 16, 0, 0);
}
// states: device-coherent (sc0|sc1 = 1|16) — bypasses stale L2s, served by L3
__device__ __forceinline__ void stage16s(const _Float16* gp, _Float16* lp) {
    __builtin_amdgcn_global_load_lds(
        (const __attribute__((address_space(1))) unsigned int*)gp,
        (__attribute__((address_space(3))) unsigned int*)lp, 16, 0, 17);
}
// device-coherent vector store (write-through; no per-element atomic amplification)
__device__ __forceinline__ void st16_sc(void* p, uint4v v) {
    asm volatile("global_store_dwordx4 %0, %1, off sc0 sc1" :: "v"(p), "v"(v) : "memory");
}
__device__ __forceinline__ void st16_sc_f(void* p, float4v v) {
    st16_sc(p, __builtin_bit_cast(uint4v, v));
}

// ---------------- prep kernels ----------------
__global__ void conv3_kernel(const float* __restrict__ w1, const float* __restrict__ w2,
                             const float* __restrict__ w3,
                             _Float16* o1h, _Float16* o1l, _Float16* o2h, _Float16* o2l,
                             _Float16* o3h, _Float16* o3l) {
    int i = blockIdx.x * 256 + threadIdx.x;
    if (i < G3H * H) {
        const int r = i >> 9, k = i & 511;
        const size_t d = (size_t)r * H + swzk(r, k);
        split_f16(w1[i], &o1h[d], &o1l[d]);
        split_f16(w2[i], &o2h[d], &o2l[d]);
        split_f16(w3[i], &o3h[d], &o3l[d]);
    }
}

__global__ void prep_kernel(const float* __restrict__ h01, const float* __restrict__ h02,
                            _Float16* h1h, _Float16* h1l, _Float16* h2h, _Float16* h2l) {
    int i = blockIdx.x * 256 + threadIdx.x;
    if (i < B * H) {
        const int r = i >> 9, k = i & 511;
        const size_t d = (size_t)r * H + swzk(r, k);
        split_f16(h01[i], &h1h[d], &h1l[d]);
        split_f16(h02[i], &h2h[d], &h2l[d]);
    }
}

// ---------------- staging: one 64x64 K-tile (A sc-coherent, W cached) ----------------
__device__ __forceinline__ void stage_tile(
    const _Float16* __restrict__ Ahp, const _Float16* __restrict__ Alp,
    const _Float16* __restrict__ Whp, const _Float16* __restrict__ Wlp,
    int m0, int n0, int k0, int tid, int wv,
    _Float16* sAh_, _Float16* sAl_, _Float16* sWh_, _Float16* sWl_)
{
    {
        const int row = tid >> 3, kc = tid & 7;
        const size_t off = (size_t)(m0 + row) * H + k0 + kc * 8;
        stage16s(Ahp + off, &sAh_[(wv * 64) * 8]);
        stage16s(Alp + off, &sAl_[(wv * 64) * 8]);
    }
    #pragma unroll
    for (int j = 0; j < 3; ++j) {
        const int cid = j * 512 + tid;
        const int gg = cid >> 9, rem = cid & 511;
        const int nr = rem >> 3, kc = rem & 7;
        const size_t off = (size_t)(gg * H + n0 + nr) * H + k0 + kc * 8;
        stage16w(Whp + off, &sWh_[(j * 512 + wv * 64) * 8]);
        stage16w(Wlp + off, &sWl_[(j * 512 + wv * 64) * 8]);
    }
}

// ---------------- one 64x64x64 tile of 3-gate split-f16 MFMA (R7-verified) ----------------
__device__ __forceinline__ void compute_tile(
    const _Float16* sAh, const _Float16* sAl,
    const _Float16* sWh, const _Float16* sWl,
    int wm, int wn, int ln, int qd, int sN,
    float4v (&accH)[4][2], float4v (&accL)[4][2])
{
    #pragma unroll
    for (int ks = 0; ks < 2; ++ks) {
        const int c = ks * 4 + qd;
        const int row = wm * 16 + ln;
        const int ai = row * 64 + ((c ^ (row & 7)) << 3);
        half8 afh = *(const half8*)&sAh[ai];
        half8 afl = *(const half8*)&sAl[ai];
        #pragma unroll
        for (int g = 0; g < 3; ++g) {
            const int s = (g < 2) ? g : sN;
            #pragma unroll
            for (int nt = 0; nt < 2; ++nt) {
                const int nr = wn * 32 + nt * 16 + ln;
                const int wi = (g * 64 + nr) * 64 + ((c ^ (nr & 7)) << 3);
                half8 bh = *(const half8*)&sWh[wi];
                half8 bl = *(const half8*)&sWl[wi];
                accH[s][nt] = __builtin_amdgcn_mfma_f32_16x16x32_f16(afh, bh, accH[s][nt], 0, 0, 0);
                accL[s][nt] = __builtin_amdgcn_mfma_f32_16x16x32_f16(afh, bl, accL[s][nt], 0, 0, 0);
                accL[s][nt] = __builtin_amdgcn_mfma_f32_16x16x32_f16(afl, bh, accL[s][nt], 0, 0, 0);
            }
        }
    }
}

// ---------------- persistent full-rollout kernel ----------------
// 256 blocks x 512 thr, 1 block/CU (LDS-forced => each XCD gets exactly 32
// blocks). n0 = 64 * measured XCD id (W slice stays in XCD-local L2);
// m0 = 64 * per-XCD atomic ticket. Cliques (same m0, one member per XCD)
// exchange state via sc0/sc1 L3-coherent accesses.
__global__ __launch_bounds__(512, 1) void gru_persist(
    const _Float16* __restrict__ wh1h, const _Float16* __restrict__ wh1l,
    const _Float16* __restrict__ wi2h, const _Float16* __restrict__ wi2l,
    const _Float16* __restrict__ wh2h, const _Float16* __restrict__ wh2l,
    const float* __restrict__ W_ih1, const float* __restrict__ W_out,
    const float* __restrict__ b_out,
    const float* __restrict__ b_ih1, const float* __restrict__ b_hh1,
    const float* __restrict__ b_ih2, const float* __restrict__ b_hh2,
    const float* __restrict__ cmds, const float* __restrict__ y0,
    const float* __restrict__ h01, const float* __restrict__ h02,
    _Float16* __restrict__ h1h, _Float16* __restrict__ h1l,   // 2 slots each
    _Float16* __restrict__ h2h, _Float16* __restrict__ h2l,
    float* __restrict__ ybuf,   // [32 cliques][8 members][320]
    float* __restrict__ out,
    uint32* __restrict__ bar,   // [32 cliques] spaced 128B
    uint32* __restrict__ mcnt)  // [8] per-XCD tickets
{
    __shared__ _Float16 sAh[2][4096], sAl[2][4096];     // 32 KB
    __shared__ _Float16 sWh[2][12288], sWl[2][12288];   // 96 KB
    __shared__ float sX[64 * 8];
    __shared__ float sWi1[3][8][64];
    __shared__ float sBi1[3][64], sBh1[3][64], sBi2[3][64], sBh2[3][64];
    __shared__ float sYp[2][64][5];
    __shared__ int sMeta[2];

    const int tid = threadIdx.x;
    const int wv = tid >> 6, lane = tid & 63;
    const int wm = wv >> 1, wn = wv & 1;
    const int ln = lane & 15, qd = lane >> 4;

    // ---- measured XCD placement + m-tile ticket ----
    if (tid == 0) {
        uint32 xcc;
        asm volatile("s_getreg_b32 %0, hwreg(HW_REG_XCC_ID)" : "=s"(xcc));
        xcc &= 7;
        const uint32 tk = __hip_atomic_fetch_add(&mcnt[xcc], 1u,
                                                 __ATOMIC_RELAXED, __HIP_MEMORY_SCOPE_AGENT)
                          & 31;
        sMeta[0] = (int)(tk * 64);     // m0
        sMeta[1] = (int)(xcc * 64);    // n0
    }
    __syncthreads();
    const int m0 = sMeta[0];
    const int n0 = sMeta[1];
    const int clique = m0 >> 6;
    const int member = n0 >> 6;

    // ---- one-time LDS fills ----
    for (int i = tid; i < 3 * 64 * 8; i += 512) {
        const int g = i >> 9, rem = i & 511, n = rem >> 3, k = rem & 7;
        sWi1[g][k][n] = W_ih1[(g * H + n0 + n) * 8 + k];
    }
    if (tid < 192) {
        const int g = tid >> 6, n = tid & 63;
        sBi1[g][n] = b_ih1[g * H + n0 + n];
        sBh1[g][n] = b_hh1[g * H + n0 + n];
        sBi2[g][n] = b_ih2[g * H + n0 + n];
        sBh2[g][n] = b_hh2[g * H + n0 + n];
    }

    // W_out columns for this block's n-slice + bias (registers)
    float wout[2][NO], bo5[NO];
    #pragma unroll
    for (int nt = 0; nt < 2; ++nt)
        #pragma unroll
        for (int o = 0; o < NO; ++o)
            wout[nt][o] = W_out[(size_t)o * H + n0 + wn * 32 + nt * 16 + ln];
    #pragma unroll
    for (int o = 0; o < NO; ++o) bo5[o] = b_out[o];

    // register-carried h_prev at this block's C-fragment positions
    float hprev1[2][4], hprev2[2][4];
    #pragma unroll
    for (int nt = 0; nt < 2; ++nt)
        #pragma unroll
        for (int r = 0; r < 4; ++r) {
            const int m = m0 + wm * 16 + qd * 4 + r;
            const int gn = n0 + wn * 32 + nt * 16 + ln;
            hprev1[nt][r] = h01[(size_t)m * H + gn];
            hprev2[nt][r] = h02[(size_t)m * H + gn];
        }

    uint32 bt = 0;
    uint32* cnt = bar + clique * 32;
    auto gbar = [&]() {
        asm volatile("s_waitcnt vmcnt(0)" ::: "memory");   // drain asm sc-stores too
        __syncthreads();
        bt += 8;
        if (tid == 0) {
            __hip_atomic_fetch_add(cnt, 1u, __ATOMIC_RELAXED, __HIP_MEMORY_SCOPE_AGENT);
            while (__hip_atomic_load(cnt, __ATOMIC_RELAXED, __HIP_MEMORY_SCOPE_AGENT) < bt)
                __builtin_amdgcn_s_sleep(2);
        }
        __syncthreads();
    };

    float4v accH[4][2], accL[4][2];
    auto zero_acc = [&]() {
        #pragma unroll
        for (int s = 0; s < 4; ++s)
            #pragma unroll
            for (int nt = 0; nt < 2; ++nt) { accH[s][nt] = (float4v)(0.f); accL[s][nt] = (float4v)(0.f); }
    };

    // gather 8 member y-partials (sc loads), add bias; fill sX; store out[:, tprev]
    auto gather_y = [&](int tprev) {
        if (tid < 80) {
            const float* base = ybuf + (size_t)clique * 8 * 320 + tid * 4;
            float4v g0, g1, g2, g3, g4, g5, g6, g7;
            asm volatile(
                "global_load_dwordx4 %0, %8, off sc0 sc1\n\t"
                "global_load_dwordx4 %1, %9, off sc0 sc1\n\t"
                "global_load_dwordx4 %2, %10, off sc0 sc1\n\t"
                "global_load_dwordx4 %3, %11, off sc0 sc1\n\t"
                "global_load_dwordx4 %4, %12, off sc0 sc1\n\t"
                "global_load_dwordx4 %5, %13, off sc0 sc1\n\t"
                "global_load_dwordx4 %6, %14, off sc0 sc1\n\t"
                "global_load_dwordx4 %7, %15, off sc0 sc1\n\t"
                "s_waitcnt vmcnt(0)"
                : "=v"(g0), "=v"(g1), "=v"(g2), "=v"(g3),
                  "=v"(g4), "=v"(g5), "=v"(g6), "=v"(g7)
                : "v"(base), "v"(base + 320), "v"(base + 640), "v"(base + 960),
                  "v"(base + 1280), "v"(base + 1600), "v"(base + 1920), "v"(base + 2240)
                : "memory");
            float4v s = g0 + g1 + g2 + g3 + g4 + g5 + g6 + g7;
            #pragma unroll
            for (int j = 0; j < 4; ++j) {
                const int e = tid * 4 + j;
                const int m = e / 5, o = e - m * 5;
                const float yv = s[j] + bo5[o];
                sX[m * 8 + o] = yv;
                if (n0 == 0)
                    out[(size_t)(m0 + m) * (T * NO) + (size_t)tprev * NO + o] = yv;
            }
        }
    };

    int si = 0;
    #pragma unroll 1
    for (int t = 0; t < T; ++t) {
        const _Float16* h1ph = h1h + (size_t)si * BHE;
        const _Float16* h1pl = h1l + (size_t)si * BHE;
        const _Float16* h2ph = h2h + (size_t)si * BHE;
        const _Float16* h2pl = h2l + (size_t)si * BHE;
        _Float16* h1nh = h1h + (size_t)(si ^ 1) * BHE;
        _Float16* h1nl = h1l + (size_t)(si ^ 1) * BHE;
        _Float16* h2nh = h2h + (size_t)(si ^ 1) * BHE;
        _Float16* h2nl = h2l + (size_t)(si ^ 1) * BHE;

        // ================= phase A: layer 1 =================
        zero_acc();
        stage_tile(h1ph, h1pl, wh1h, wh1l, m0, n0, 0, tid, wv,
                   sAh[0], sAl[0], sWh[0], sWl[0]);
        if (t == 0) {
            if (tid < 64) {
                #pragma unroll
                for (int o2 = 0; o2 < NO; ++o2)
                    sX[tid * 8 + o2] = y0[(size_t)(m0 + tid) * NO + o2];
            }
        } else {
            gather_y(t - 1);
        }
        if (tid < 64) {
            #pragma unroll
            for (int c = 0; c < NC; ++c)
                sX[tid * 8 + NO + c] = cmds[(size_t)t * B * NC + (size_t)(m0 + tid) * NC + c];
        }
        for (int it = 0; it < 8; ++it) {
            const int buf = it & 1;
            __syncthreads();
            if (it + 1 < 8)
                stage_tile(h1ph, h1pl, wh1h, wh1l, m0, n0, (it + 1) * 64, tid, wv,
                           sAh[buf ^ 1], sAl[buf ^ 1], sWh[buf ^ 1], sWl[buf ^ 1]);
            compute_tile(sAh[buf], sAl[buf], sWh[buf], sWl[buf], wm, wn, ln, qd, 3, accH, accL);
        }
        // epilogue layer 1 -> swizzled LDS tile (sA*[0] free: last compute used buf 1)
        #pragma unroll
        for (int nt = 0; nt < 2; ++nt) {
            const int gnl = wn * 32 + nt * 16 + ln;
            #pragma unroll
            for (int r = 0; r < 4; ++r) {
                const int mloc = wm * 16 + qd * 4 + r;
                float giR = sBi1[0][gnl], giZ = sBi1[1][gnl], giN = sBi1[2][gnl];
                #pragma unroll
                for (int k = 0; k < 8; ++k) {
                    const float xv = sX[mloc * 8 + k];
                    giR = fmaf(xv, sWi1[0][k][gnl], giR);
                    giZ = fmaf(xv, sWi1[1][k][gnl], giZ);
                    giN = fmaf(xv, sWi1[2][k][gnl], giN);
                }
                const float gR = giR + sBh1[0][gnl] + accH[0][nt][r] + accL[0][nt][r] * INV_LO;
                const float gZ = giZ + sBh1[1][gnl] + accH[1][nt][r] + accL[1][nt][r] * INV_LO;
                const float gNh = sBh1[2][gnl] + accH[3][nt][r] + accL[3][nt][r] * INV_LO;
                const float R = sigmoidf_(gR), Z = sigmoidf_(gZ);
                const float N = tanhf(fmaf(R, gNh, giN));
                const float hv = (1.f - Z) * N + Z * hprev1[nt][r];
                hprev1[nt][r] = hv;
                _Float16 hh_, ll_;
                split_f16(hv, &hh_, &ll_);
                const int li = mloc * 64 + (((gnl >> 3) ^ (mloc & 7)) << 3) + (gnl & 7);
                sAh[0][li] = hh_;
                sAl[0][li] = ll_;
            }
        }
        __syncthreads();
        {   // 16B sc-stores of this block's h1n slice
            const int row = tid >> 3, s = tid & 7;
            const size_t g = (size_t)(m0 + row) * H + n0 + s * 8;
            st16_sc(h1nh + g, *(const uint4v*)&sAh[0][row * 64 + s * 8]);
            st16_sc(h1nl + g, *(const uint4v*)&sAl[0][row * 64 + s * 8]);
        }
        gbar();

        // ================= phase B: layer 2 =================
        zero_acc();
        stage_tile(h1nh, h1nl, wi2h, wi2l, m0, n0, 0, tid, wv,
                   sAh[0], sAl[0], sWh[0], sWl[0]);
        for (int it = 0; it < 16; ++it) {
            const int buf = it & 1;
            __syncthreads();
            if (it + 1 < 16) {
                const int k0 = ((it + 1) & 7) * 64;
                if (it + 1 < 8)
                    stage_tile(h1nh, h1nl, wi2h, wi2l, m0, n0, k0, tid, wv,
                               sAh[buf ^ 1], sAl[buf ^ 1], sWh[buf ^ 1], sWl[buf ^ 1]);
                else
                    stage_tile(h2ph, h2pl, wh2h, wh2l, m0, n0, k0, tid, wv,
                               sAh[buf ^ 1], sAl[buf ^ 1], sWh[buf ^ 1], sWl[buf ^ 1]);
            }
            compute_tile(sAh[buf], sAl[buf], sWh[buf], sWl[buf],
                         wm, wn, ln, qd, (it < 8) ? 2 : 3, accH, accL);
        }
        // epilogue layer 2 + y-partials
        float yp[4][NO];
        #pragma unroll
        for (int r = 0; r < 4; ++r)
            #pragma unroll
            for (int o = 0; o < NO; ++o) yp[r][o] = 0.f;
        #pragma unroll
        for (int nt = 0; nt < 2; ++nt) {
            const int gnl = wn * 32 + nt * 16 + ln;
            #pragma unroll
            for (int r = 0; r < 4; ++r) {
                const int mloc = wm * 16 + qd * 4 + r;
                const float gR = sBi2[0][gnl] + sBh2[0][gnl]
                    + accH[0][nt][r] + accL[0][nt][r] * INV_LO;
                const float gZ = sBi2[1][gnl] + sBh2[1][gnl]
                    + accH[1][nt][r] + accL[1][nt][r] * INV_LO;
                const float gNi = sBi2[2][gnl] + accH[2][nt][r] + accL[2][nt][r] * INV_LO;
                const float gNh = sBh2[2][gnl] + accH[3][nt][r] + accL[3][nt][r] * INV_LO;
                const float R = sigmoidf_(gR), Z = sigmoidf_(gZ);
                const float N = tanhf(fmaf(R, gNh, gNi));
                const float hv = (1.f - Z) * N + Z * hprev2[nt][r];
                hprev2[nt][r] = hv;
                #pragma unroll
                for (int o = 0; o < NO; ++o) yp[r][o] = fmaf(hv, wout[nt][o], yp[r][o]);
                _Float16 hh_, ll_;
                split_f16(hv, &hh_, &ll_);
                const int li = mloc * 64 + (((gnl >> 3) ^ (mloc & 7)) << 3) + (gnl & 7);
                sAh[0][li] = hh_;
                sAl[0][li] = ll_;
            }
        }
        // reduce y-partials over ln lanes (lane bits 0..3)
        #pragma unroll
        for (int off = 1; off < 16; off <<= 1)
            #pragma unroll
            for (int r = 0; r < 4; ++r)
                #pragma unroll
                for (int o = 0; o < NO; ++o)
                    yp[r][o] += __shfl_xor(yp[r][o], off, 64);
        if (ln == 0) {
            #pragma unroll
            for (int r = 0; r < 4; ++r)
                #pragma unroll
                for (int o = 0; o < NO; ++o)
                    sYp[wn][wm * 16 + qd * 4 + r][o] = yp[r][o];
        }
        __syncthreads();
        {   // 16B sc-stores of h2n slice
            const int row = tid >> 3, s = tid & 7;
            const size_t g = (size_t)(m0 + row) * H + n0 + s * 8;
            st16_sc(h2nh + g, *(const uint4v*)&sAh[0][row * 64 + s * 8]);
            st16_sc(h2nl + g, *(const uint4v*)&sAl[0][row * 64 + s * 8]);
        }
        if (tid < 80) {   // block's y-partial (sum of both wn halves) -> clique buffer
            float4v v;
            #pragma unroll
            for (int j = 0; j < 4; ++j) {
                const int e = tid * 4 + j;
                v[j] = ((const float*)sYp)[e] + ((const float*)sYp)[320 + e];
            }
            st16_sc_f(ybuf + ((size_t)clique * 8 + member) * 320 + tid * 4, v);
        }
        gbar();
        si ^= 1;
    }

    // final y_{T-1}
    gather_y(T - 1);
}

extern "C" void kernel_launch(void* const* d_in, const int* in_sizes, int n_in,
                              void* d_out, int out_size, void* d_ws, size_t ws_size,
                              hipStream_t stream) {
    (void)in_sizes; (void)n_in; (void)out_size; (void)ws_size;
    const float* cmds  = (const float*)d_in[1];
    const float* y0    = (const float*)d_in[2];
    const float* h01   = (const float*)d_in[3];
    const float* h02   = (const float*)d_in[4];
    const float* W_ih1 = (const float*)d_in[5];
    const float* W_hh1 = (const float*)d_in[6];
    const float* b_ih1 = (const float*)d_in[7];
    const float* b_hh1 = (const float*)d_in[8];
    const float* W_ih2 = (const float*)d_in[9];
    const float* W_hh2 = (const float*)d_in[10];
    const float* b_ih2 = (const float*)d_in[11];
    const float* b_hh2 = (const float*)d_in[12];
    const float* W_out = (const float*)d_in[13];
    const float* b_out = (const float*)d_in[14];
    float* out = (float*)d_out;

    // ---- workspace (~26.5 MB) ----
    char* ws = (char*)d_ws;
    size_t o = 0;
    const size_t WSZ = (size_t)G3H * H * sizeof(_Float16);
    _Float16* wh1h = (_Float16*)(ws + o); o += WSZ;
    _Float16* wh1l = (_Float16*)(ws + o); o += WSZ;
    _Float16* wi2h = (_Float16*)(ws + o); o += WSZ;
    _Float16* wi2l = (_Float16*)(ws + o); o += WSZ;
    _Float16* wh2h = (_Float16*)(ws + o); o += WSZ;
    _Float16* wh2l = (_Float16*)(ws + o); o += WSZ;
    _Float16* h1h = (_Float16*)(ws + o); o += 2 * BHE * 2;
    _Float16* h1l = (_Float16*)(ws + o); o += 2 * BHE * 2;
    _Float16* h2h = (_Float16*)(ws + o); o += 2 * BHE * 2;
    _Float16* h2l = (_Float16*)(ws + o); o += 2 * BHE * 2;
    float* ybuf = (float*)(ws + o); o += (size_t)32 * 8 * 320 * 4;
    uint32* bar = (uint32*)(ws + o); o += 32 * 128;
    uint32* mcnt = (uint32*)(ws + o); o += 128;

    (void)hipMemsetAsync(bar, 0, 32 * 128 + 128, stream);
    conv3_kernel<<<(G3H * H + 255) / 256, 256, 0, stream>>>(
        W_hh1, W_ih2, W_hh2, wh1h, wh1l, wi2h, wi2l, wh2h, wh2l);
    prep_kernel<<<(B * H + 255) / 256, 256, 0, stream>>>(h01, h02, h1h, h1l, h2h, h2l);

    gru_persist<<<256, 512, 0, stream>>>(
        wh1h, wh1l, wi2h, wi2l, wh2h, wh2l,
        W_ih1, W_out, b_out,
        b_ih1, b_hh1, b_ih2, b_hh2,
        cmds, y0, h01, h02,
        h1h, h1l, h2h, h2l,
        ybuf, out, bar, mcnt);
}

// Round 11
// 8866.467 us; speedup vs baseline: 1.2814x; 1.2814x over previous
//
#include <hip/hip_runtime.h>
#include <math.h>

// Problem constants
#define B 2048
#define T 128
#define H 512
#define NC 3
#define NO 5
#define G3H 1536
#define BHE ((size_t)B * H)

typedef _Float16 half8 __attribute__((ext_vector_type(8)));
typedef float float4v __attribute__((ext_vector_type(4)));
typedef unsigned int uint32;
typedef unsigned int uint4v __attribute__((ext_vector_type(4)));

#define LO_SCALE 1024.0f
#define INV_LO (1.0f / 1024.0f)
#define F16_MIN_NORM 6.103515625e-05f

__device__ __forceinline__ float sigmoidf_(float x) { return 1.0f / (1.0f + __expf(-x)); }

__device__ __forceinline__ void split_f16(float a, _Float16* hi, _Float16* lo) {
    _Float16 h = (_Float16)a;
    if (fabsf(a) < F16_MIN_NORM) h = (_Float16)0.0f;
    *hi = h;
    *lo = (_Float16)((a - (float)h) * LO_SCALE);
}

// element (row,k) of a 512-col matrix stored at row*512 + swzk32(row,k):
// 16B chunk j=(k>>3)&3 within each 32-k group lands in slot j ^ ((row>>1)&3).
// -> staging is a positional linear copy; MFMA fragment ds_reads spread 16
//    lanes over 8 bank-groups (2-way = free).
__device__ __forceinline__ int swzk32(int row, int k) {
    return (k & ~31) | (((((k >> 3) & 3) ^ ((row >> 1) & 3))) << 3) | (k & 7);
}

// weights: normal cached async 16B global->LDS (stays in XCD L2)
__device__ __forceinline__ void stage16w(const _Float16* gp, _Float16* lp) {
    __builtin_amdgcn_global_load_lds(
        (const __attribute__((address_space(1))) unsigned int*)gp,
        (__attribute__((address_space(3))) unsigned int*)lp, 16, 0, 0);
}
// states: device-coherent (sc0|sc1) — bypasses stale L2s, served by L3
__device__ __forceinline__ void stage16s(const _Float16* gp, _Float16* lp) {
    __builtin_amdgcn_global_load_lds(
        (const __attribute__((address_space(1))) unsigned int*)gp,
        (__attribute__((address_space(3))) unsigned int*)lp, 16, 0, 17);
}
// device-coherent vector store (write-through)
__device__ __forceinline__ void st16_sc(void* p, uint4v v) {
    asm volatile("global_store_dwordx4 %0, %1, off sc0 sc1" :: "v"(p), "v"(v) : "memory");
}
__device__ __forceinline__ void st16_sc_f(void* p, float4v v) {
    st16_sc(p, __builtin_bit_cast(uint4v, v));
}

// ---------------- prep kernels ----------------
__global__ void conv3_kernel(const float* __restrict__ w1, const float* __restrict__ w2,
                             const float* __restrict__ w3,
                             _Float16* o1h, _Float16* o1l, _Float16* o2h, _Float16* o2l,
                             _Float16* o3h, _Float16* o3l) {
    int i = blockIdx.x * 256 + threadIdx.x;
    if (i < G3H * H) {
        const int r = i >> 9, k = i & 511;
        const size_t d = (size_t)r * H + swzk32(r, k);
        split_f16(w1[i], &o1h[d], &o1l[d]);
        split_f16(w2[i], &o2h[d], &o2l[d]);
        split_f16(w3[i], &o3h[d], &o3l[d]);
    }
}

__global__ void prep_kernel(const float* __restrict__ h01, const float* __restrict__ h02,
                            _Float16* h1h, _Float16* h1l, _Float16* h2h, _Float16* h2l) {
    int i = blockIdx.x * 256 + threadIdx.x;
    if (i < B * H) {
        const int r = i >> 9, k = i & 511;
        const size_t d = (size_t)r * H + swzk32(r, k);
        split_f16(h01[i], &h1h[d], &h1l[d]);
        split_f16(h02[i], &h2h[d], &h2l[d]);
    }
}

// ---------------- staging one 64x64x32 tile (4 loads/thread) ----------------
// A: 256 chunks hi (waves 0-3) + 256 lo (waves 4-7); W: 768 hi + 768 lo, 3/thread.
__device__ __forceinline__ void stage32(
    const _Float16* __restrict__ Ahp, const _Float16* __restrict__ Alp,
    const _Float16* __restrict__ Whp, const _Float16* __restrict__ Wlp,
    int m0, int n0, int k0, int wv, int lane,
    _Float16* bAh, _Float16* bAl, _Float16* bWh, _Float16* bWl)
{
    {   // A tile: positional copy of the swizzled 32-k group
        const int c = (wv & 3) * 64 + lane;     // chunk 0..255
        const int row = c >> 2, kc = c & 3;
        const size_t off = (size_t)(m0 + row) * H + k0 + kc * 8;
        if (wv < 4) stage16s(Ahp + off, bAh + (wv & 3) * 512);
        else        stage16s(Alp + off, bAl + (wv & 3) * 512);
    }
    #pragma unroll
    for (int j = 0; j < 3; ++j) {
        const int gcb = j * 512 + wv * 64;      // wave-uniform base chunk
        const bool hi = (gcb < 768);
        const int cb = hi ? gcb : gcb - 768;
        const int c = cb + lane;                // chunk 0..767
        const int row = c >> 2, kc = c & 3;     // row 0..191 (3 gates x 64 n)
        const size_t off = (size_t)((row >> 6) * H + n0 + (row & 63)) * H + k0 + kc * 8;
        if (hi) stage16w(Whp + off, bWh + cb * 8);
        else    stage16w(Wlp + off, bWl + cb * 8);
    }
}

// ---------------- one 64x64x32 tile of 3-gate split-f16 MFMA ----------------
__device__ __forceinline__ void compute32(
    const _Float16* bAh, const _Float16* bAl,
    const _Float16* bWh, const _Float16* bWl,
    int wm, int wn, int ln, int qd, int sN,
    float4v (&accH)[4][2], float4v (&accL)[4][2])
{
    const int row = wm * 16 + ln;
    const int ai = row * 32 + ((qd ^ ((row >> 1) & 3)) << 3);
    half8 afh = *(const half8*)&bAh[ai];
    half8 afl = *(const half8*)&bAl[ai];
    #pragma unroll
    for (int g = 0; g < 3; ++g) {
        const int s = (g < 2) ? g : sN;
        #pragma unroll
        for (int nt = 0; nt < 2; ++nt) {
            const int nr = wn * 32 + nt * 16 + ln;
            const int wi = (g * 64 + nr) * 32 + ((qd ^ ((nr >> 1) & 3)) << 3);
            half8 bh = *(const half8*)&bWh[wi];
            half8 bl = *(const half8*)&bWl[wi];
            accH[s][nt] = __builtin_amdgcn_mfma_f32_16x16x32_f16(afh, bh, accH[s][nt], 0, 0, 0);
            accL[s][nt] = __builtin_amdgcn_mfma_f32_16x16x32_f16(afh, bl, accL[s][nt], 0, 0, 0);
            accL[s][nt] = __builtin_amdgcn_mfma_f32_16x16x32_f16(afl, bh, accL[s][nt], 0, 0, 0);
        }
    }
}

// ---------------- persistent full-rollout kernel ----------------
// 256 blocks x 512 thr, 1 block/CU. n0 = 64*XCC_ID (W slice L2-resident),
// m0 = 64*per-XCD ticket. Quad-buffered K=32 pipeline with raw s_barrier +
// manual vmcnt (loads stay in flight across barriers).
__global__ __launch_bounds__(512, 1) void gru_persist(
    const _Float16* __restrict__ wh1h, const _Float16* __restrict__ wh1l,
    const _Float16* __restrict__ wi2h, const _Float16* __restrict__ wi2l,
    const _Float16* __restrict__ wh2h, const _Float16* __restrict__ wh2l,
    const float* __restrict__ W_ih1, const float* __restrict__ W_out,
    const float* __restrict__ b_out,
    const float* __restrict__ b_ih1, const float* __restrict__ b_hh1,
    const float* __restrict__ b_ih2, const float* __restrict__ b_hh2,
    const float* __restrict__ cmds, const float* __restrict__ y0,
    const float* __restrict__ h01, const float* __restrict__ h02,
    _Float16* __restrict__ h1h, _Float16* __restrict__ h1l,   // 2 slots each
    _Float16* __restrict__ h2h, _Float16* __restrict__ h2l,
    float* __restrict__ ybuf,   // [32 cliques][8 members][320]
    float* __restrict__ out,
    uint32* __restrict__ bar,   // [32 cliques] spaced 128B
    uint32* __restrict__ mcnt)  // [8] per-XCD tickets
{
    __shared__ _Float16 sAh4[4][2048], sAl4[4][2048];   // 32 KB
    __shared__ _Float16 sWh4[4][6144], sWl4[4][6144];   // 96 KB
    __shared__ float sX[64 * 8];
    __shared__ float sWi1[3][8][64];
    __shared__ float sBi1[3][64], sBh1[3][64], sBi2[3][64], sBh2[3][64];
    __shared__ float sYp[2][64][5];
    __shared__ int sMeta[2];

    const int tid = threadIdx.x;
    const int wv = tid >> 6, lane = tid & 63;
    const int wm = wv >> 1, wn = wv & 1;
    const int ln = lane & 15, qd = lane >> 4;

    // ---- measured XCD placement + m-tile ticket ----
    if (tid == 0) {
        uint32 xcc;
        asm volatile("s_getreg_b32 %0, hwreg(HW_REG_XCC_ID)" : "=s"(xcc));
        xcc &= 7;
        const uint32 tk = __hip_atomic_fetch_add(&mcnt[xcc], 1u,
                                                 __ATOMIC_RELAXED, __HIP_MEMORY_SCOPE_AGENT)
                          & 31;
        sMeta[0] = (int)(tk * 64);     // m0
        sMeta[1] = (int)(xcc * 64);    // n0
    }
    __syncthreads();
    const int m0 = sMeta[0];
    const int n0 = sMeta[1];
    const int clique = m0 >> 6;
    const int member = n0 >> 6;

    // ---- one-time LDS fills ----
    for (int i = tid; i < 3 * 64 * 8; i += 512) {
        const int g = i >> 9, rem = i & 511, n = rem >> 3, k = rem & 7;
        sWi1[g][k][n] = W_ih1[(g * H + n0 + n) * 8 + k];
    }
    if (tid < 192) {
        const int g = tid >> 6, n = tid & 63;
        sBi1[g][n] = b_ih1[g * H + n0 + n];
        sBh1[g][n] = b_hh1[g * H + n0 + n];
        sBi2[g][n] = b_ih2[g * H + n0 + n];
        sBh2[g][n] = b_hh2[g * H + n0 + n];
    }

    float wout[2][NO], bo5[NO];
    #pragma unroll
    for (int nt = 0; nt < 2; ++nt)
        #pragma unroll
        for (int o = 0; o < NO; ++o)
            wout[nt][o] = W_out[(size_t)o * H + n0 + wn * 32 + nt * 16 + ln];
    #pragma unroll
    for (int o = 0; o < NO; ++o) bo5[o] = b_out[o];

    float hprev1[2][4], hprev2[2][4];
    #pragma unroll
    for (int nt = 0; nt < 2; ++nt)
        #pragma unroll
        for (int r = 0; r < 4; ++r) {
            const int m = m0 + wm * 16 + qd * 4 + r;
            const int gn = n0 + wn * 32 + nt * 16 + ln;
            hprev1[nt][r] = h01[(size_t)m * H + gn];
            hprev2[nt][r] = h02[(size_t)m * H + gn];
        }
    __syncthreads();

    uint32 bt = 0;
    uint32* cnt = bar + clique * 32;
    auto gbar = [&]() {
        asm volatile("s_waitcnt vmcnt(0)" ::: "memory");
        __syncthreads();
        bt += 8;
        if (tid == 0) {
            __hip_atomic_fetch_add(cnt, 1u, __ATOMIC_RELAXED, __HIP_MEMORY_SCOPE_AGENT);
            while (__hip_atomic_load(cnt, __ATOMIC_RELAXED, __HIP_MEMORY_SCOPE_AGENT) < bt)
                __builtin_amdgcn_s_sleep(2);
        }
        __syncthreads();
    };

    float4v accH[4][2], accL[4][2];
    auto zero_acc = [&]() {
        #pragma unroll
        for (int s = 0; s < 4; ++s)
            #pragma unroll
            for (int nt = 0; nt < 2; ++nt) { accH[s][nt] = (float4v)(0.f); accL[s][nt] = (float4v)(0.f); }
    };

    auto gather_y = [&](int tprev) {
        if (tid < 80) {
            const float* base = ybuf + (size_t)clique * 8 * 320 + tid * 4;
            float4v g0, g1, g2, g3, g4, g5, g6, g7;
            asm volatile(
                "global_load_dwordx4 %0, %8, off sc0 sc1\n\t"
                "global_load_dwordx4 %1, %9, off sc0 sc1\n\t"
                "global_load_dwordx4 %2, %10, off sc0 sc1\n\t"
                "global_load_dwordx4 %3, %11, off sc0 sc1\n\t"
                "global_load_dwordx4 %4, %12, off sc0 sc1\n\t"
                "global_load_dwordx4 %5, %13, off sc0 sc1\n\t"
                "global_load_dwordx4 %6, %14, off sc0 sc1\n\t"
                "global_load_dwordx4 %7, %15, off sc0 sc1\n\t"
                "s_waitcnt vmcnt(0)"
                : "=v"(g0), "=v"(g1), "=v"(g2), "=v"(g3),
                  "=v"(g4), "=v"(g5), "=v"(g6), "=v"(g7)
                : "v"(base), "v"(base + 320), "v"(base + 640), "v"(base + 960),
                  "v"(base + 1280), "v"(base + 1600), "v"(base + 1920), "v"(base + 2240)
                : "memory");
            float4v s = g0 + g1 + g2 + g3 + g4 + g5 + g6 + g7;
            #pragma unroll
            for (int j = 0; j < 4; ++j) {
                const int e = tid * 4 + j;
                const int m = e / 5, o = e - m * 5;
                const float yv = s[j] + bo5[o];
                sX[m * 8 + o] = yv;
                if (n0 == 0)
                    out[(size_t)(m0 + m) * (T * NO) + (size_t)tprev * NO + o] = yv;
            }
        }
    };

    // deep-pipelined phase runner: quad buffer, depth-3 prefetch, raw barriers
    auto pipeline = [&](int total, auto stageFn, auto snFn) {
        stageFn(0, 0); stageFn(1, 1); stageFn(2, 2);
        #pragma unroll 1
        for (int it = 0; it < total; ++it) {
            if (it < total - 2)       asm volatile("s_waitcnt vmcnt(8)" ::: "memory");
            else if (it == total - 2) asm volatile("s_waitcnt vmcnt(4)" ::: "memory");
            else                      asm volatile("s_waitcnt vmcnt(0)" ::: "memory");
            asm volatile("s_barrier" ::: "memory");
            if (it + 3 < total) stageFn(it + 3, (it + 3) & 3);
            const int b_ = it & 3;
            compute32(sAh4[b_], sAl4[b_], sWh4[b_], sWl4[b_],
                      wm, wn, ln, qd, snFn(it), accH, accL);
        }
    };

    // epilogue store helper: swizzled 64x64 tile (hi in sAh4[0..1], lo in sAl4[0..1])
    auto store_tile = [&](_Float16* dsth, _Float16* dstl) {
        __syncthreads();
        const int row = tid >> 3, s = tid & 7;
        const size_t g = (size_t)(m0 + row) * H + n0 + s * 8;
        const _Float16* th = &sAh4[0][0];
        const _Float16* tl = &sAl4[0][0];
        st16_sc(dsth + g, *(const uint4v*)&th[row * 64 + s * 8]);
        st16_sc(dstl + g, *(const uint4v*)&tl[row * 64 + s * 8]);
    };

    int si = 0;
    #pragma unroll 1
    for (int t = 0; t < T; ++t) {
        const _Float16* h1ph = h1h + (size_t)si * BHE;
        const _Float16* h1pl = h1l + (size_t)si * BHE;
        const _Float16* h2ph = h2h + (size_t)si * BHE;
        const _Float16* h2pl = h2l + (size_t)si * BHE;
        _Float16* h1nh = h1h + (size_t)(si ^ 1) * BHE;
        _Float16* h1nl = h1l + (size_t)(si ^ 1) * BHE;
        _Float16* h2nh = h2h + (size_t)(si ^ 1) * BHE;
        _Float16* h2nl = h2l + (size_t)(si ^ 1) * BHE;

        // ---- x_t = [y_{t-1}, cmd_t] (before staging: keeps vmcnt accounting clean) ----
        if (t == 0) {
            if (tid < 64) {
                #pragma unroll
                for (int o2 = 0; o2 < NO; ++o2)
                    sX[tid * 8 + o2] = y0[(size_t)(m0 + tid) * NO + o2];
            }
        } else {
            gather_y(t - 1);
        }
        if (tid < 64) {
            #pragma unroll
            for (int c = 0; c < NC; ++c)
                sX[tid * 8 + NO + c] = cmds[(size_t)t * B * NC + (size_t)(m0 + tid) * NC + c];
        }
        asm volatile("s_waitcnt lgkmcnt(0)" ::: "memory");  // publish sX before raw barriers

        // ================= phase A: layer 1 (16 K-tiles) =================
        zero_acc();
        auto stA = [&](int tt, int buf) {
            stage32(h1ph, h1pl, wh1h, wh1l, m0, n0, tt * 32, wv, lane,
                    sAh4[buf], sAl4[buf], sWh4[buf], sWl4[buf]);
        };
        pipeline(16, stA, [](int) { return 3; });

        #pragma unroll
        for (int nt = 0; nt < 2; ++nt) {
            const int gnl = wn * 32 + nt * 16 + ln;
            #pragma unroll
            for (int r = 0; r < 4; ++r) {
                const int mloc = wm * 16 + qd * 4 + r;
                float giR = sBi1[0][gnl], giZ = sBi1[1][gnl], giN = sBi1[2][gnl];
                #pragma unroll
                for (int k = 0; k < 8; ++k) {
                    const float xv = sX[mloc * 8 + k];
                    giR = fmaf(xv, sWi1[0][k][gnl], giR);
                    giZ = fmaf(xv, sWi1[1][k][gnl], giZ);
                    giN = fmaf(xv, sWi1[2][k][gnl], giN);
                }
                const float gR = giR + sBh1[0][gnl] + accH[0][nt][r] + accL[0][nt][r] * INV_LO;
                const float gZ = giZ + sBh1[1][gnl] + accH[1][nt][r] + accL[1][nt][r] * INV_LO;
                const float gNh = sBh1[2][gnl] + accH[3][nt][r] + accL[3][nt][r] * INV_LO;
                const float R = sigmoidf_(gR), Z = sigmoidf_(gZ);
                const float N = tanhf(fmaf(R, gNh, giN));
                const float hv = (1.f - Z) * N + Z * hprev1[nt][r];
                hprev1[nt][r] = hv;
                _Float16 hh_, ll_;
                split_f16(hv, &hh_, &ll_);
                const int li = mloc * 64 + (gnl & ~31)
                    + ((((gnl >> 3) & 3) ^ ((mloc >> 1) & 3)) << 3) + (gnl & 7);
                (&sAh4[0][0])[li] = hh_;
                (&sAl4[0][0])[li] = ll_;
            }
        }
        store_tile(h1nh, h1nl);
        gbar();

        // ================= phase B: layer 2 (32 K-tiles) =================
        zero_acc();
        auto stB = [&](int tt, int buf) {
            if (tt < 16)
                stage32(h1nh, h1nl, wi2h, wi2l, m0, n0, tt * 32, wv, lane,
                        sAh4[buf], sAl4[buf], sWh4[buf], sWl4[buf]);
            else
                stage32(h2ph, h2pl, wh2h, wh2l, m0, n0, (tt - 16) * 32, wv, lane,
                        sAh4[buf], sAl4[buf], sWh4[buf], sWl4[buf]);
        };
        pipeline(32, stB, [](int it) { return (it < 16) ? 2 : 3; });

        float yp[4][NO];
        #pragma unroll
        for (int r = 0; r < 4; ++r)
            #pragma unroll
            for (int o = 0; o < NO; ++o) yp[r][o] = 0.f;
        #pragma unroll
        for (int nt = 0; nt < 2; ++nt) {
            const int gnl = wn * 32 + nt * 16 + ln;
            #pragma unroll
            for (int r = 0; r < 4; ++r) {
                const int mloc = wm * 16 + qd * 4 + r;
                const float gR = sBi2[0][gnl] + sBh2[0][gnl]
                    + accH[0][nt][r] + accL[0][nt][r] * INV_LO;
                const float gZ = sBi2[1][gnl] + sBh2[1][gnl]
                    + accH[1][nt][r] + accL[1][nt][r] * INV_LO;
                const float gNi = sBi2[2][gnl] + accH[2][nt][r] + accL[2][nt][r] * INV_LO;
                const float gNh = sBh2[2][gnl] + accH[3][nt][r] + accL[3][nt][r] * INV_LO;
                const float R = sigmoidf_(gR), Z = sigmoidf_(gZ);
                const float N = tanhf(fmaf(R, gNh, gNi));
                const float hv = (1.f - Z) * N + Z * hprev2[nt][r];
                hprev2[nt][r] = hv;
                #pragma unroll
                for (int o = 0; o < NO; ++o) yp[r][o] = fmaf(hv, wout[nt][o], yp[r][o]);
                _Float16 hh_, ll_;
                split_f16(hv, &hh_, &ll_);
                const int li = mloc * 64 + (gnl & ~31)
                    + ((((gnl >> 3) & 3) ^ ((mloc >> 1) & 3)) << 3) + (gnl & 7);
                (&sAh4[0][0])[li] = hh_;
                (&sAl4[0][0])[li] = ll_;
            }
        }
        // reduce y-partials over ln lanes
        #pragma unroll
        for (int off = 1; off < 16; off <<= 1)
            #pragma unroll
            for (int r = 0; r < 4; ++r)
                #pragma unroll
                for (int o = 0; o < NO; ++o)
                    yp[r][o] += __shfl_xor(yp[r][o], off, 64);
        if (ln == 0) {
            #pragma unroll
            for (int r = 0; r < 4; ++r)
                #pragma unroll
                for (int o = 0; o < NO; ++o)
                    sYp[wn][wm * 16 + qd * 4 + r][o] = yp[r][o];
        }
        store_tile(h2nh, h2nl);
        if (tid < 80) {
            float4v v;
            #pragma unroll
            for (int j = 0; j < 4; ++j) {
                const int e = tid * 4 + j;
                v[j] = ((const float*)sYp)[e] + ((const float*)sYp)[320 + e];
            }
            st16_sc_f(ybuf + ((size_t)clique * 8 + member) * 320 + tid * 4, v);
        }
        gbar();
        si ^= 1;
    }

    gather_y(T - 1);
}

extern "C" void kernel_launch(void* const* d_in, const int* in_sizes, int n_in,
                              void* d_out, int out_size, void* d_ws, size_t ws_size,
                              hipStream_t stream) {
    (void)in_sizes; (void)n_in; (void)out_size; (void)ws_size;
    const float* cmds  = (const float*)d_in[1];
    const float* y0    = (const float*)d_in[2];
    const float* h01   = (const float*)d_in[3];
    const float* h02   = (const float*)d_in[4];
    const float* W_ih1 = (const float*)d_in[5];
    const float* W_hh1 = (const float*)d_in[6];
    const float* b_ih1 = (const float*)d_in[7];
    const float* b_hh1 = (const float*)d_in[8];
    const float* W_ih2 = (const float*)d_in[9];
    const float* W_hh2 = (const float*)d_in[10];
    const float* b_ih2 = (const float*)d_in[11];
    const float* b_hh2 = (const float*)d_in[12];
    const float* W_out = (const float*)d_in[13];
    const float* b_out = (const float*)d_in[14];
    float* out = (float*)d_out;

    // ---- workspace (~26.5 MB) ----
    char* ws = (char*)d_ws;
    size_t o = 0;
    const size_t WSZ = (size_t)G3H * H * sizeof(_Float16);
    _Float16* wh1h = (_Float16*)(ws + o); o += WSZ;
    _Float16* wh1l = (_Float16*)(ws + o); o += WSZ;
    _Float16* wi2h = (_Float16*)(ws + o); o += WSZ;
    _Float16* wi2l = (_Float16*)(ws + o); o += WSZ;
    _Float16* wh2h = (_Float16*)(ws + o); o += WSZ;
    _Float16* wh2l = (_Float16*)(ws + o); o += WSZ;
    _Float16* h1h = (_Float16*)(ws + o); o += 2 * BHE * 2;
    _Float16* h1l = (_Float16*)(ws + o); o += 2 * BHE * 2;
    _Float16* h2h = (_Float16*)(ws + o); o += 2 * BHE * 2;
    _Float16* h2l = (_Float16*)(ws + o); o += 2 * BHE * 2;
    float* ybuf = (float*)(ws + o); o += (size_t)32 * 8 * 320 * 4;
    uint32* bar = (uint32*)(ws + o); o += 32 * 128;
    uint32* mcnt = (uint32*)(ws + o); o += 128;

    (void)hipMemsetAsync(bar, 0, 32 * 128 + 128, stream);
    conv3_kernel<<<(G3H * H + 255) / 256, 256, 0, stream>>>(
        W_hh1, W_ih2, W_hh2, wh1h, wh1l, wi2h, wi2l, wh2h, wh2l);
    prep_kernel<<<(B * H + 255) / 256, 256, 0, stream>>>(h01, h02, h1h, h1l, h2h, h2l);

    gru_persist<<<256, 512, 0, stream>>>(
        wh1h, wh1l, wi2h, wi2l, wh2h, wh2l,
        W_ih1, W_out, b_out,
        b_ih1, b_hh1, b_ih2, b_hh2,
        cmds, y0, h01, h02,
        h1h, h1l, h2h, h2l,
        ybuf, out, bar, mcnt);
}